// Round 9
// baseline (2209.105 us; speedup 1.0000x reference)
//
#include <hip/hip_runtime.h>
#include <stdint.h>

// Problem constants (fixed by reference)
#define NN 100000      // nodes
#define NE 1600000     // edges
#define K_DIM 128      // IN_DIM == HID_DIM

// Coarse binning
#define BSH 7                                   // 128 nodes per bucket
#define NBKT ((NN + (1 << BSH) - 1) >> BSH)     // 782 buckets
#define EPT 32                                  // edges per thread, pass 1
#define BIN_CHUNK (256 * EPT)                   // 8192 edges per block
#define CAP 2560                                // staging cap/bucket (mean 2048, +11 sigma)

typedef unsigned int uint32;
typedef unsigned short ushort16;
typedef __attribute__((ext_vector_type(8))) short bf16x8;
typedef __attribute__((ext_vector_type(4))) float f32x4;

__device__ __forceinline__ ushort16 f2bf(float f) {
    uint32 u = __float_as_uint(f);
    u += 0x7fffu + ((u >> 16) & 1u);   // round-to-nearest-even
    return (ushort16)(u >> 16);
}
__device__ __forceinline__ float bf_lo(uint32 u) { return __uint_as_float(u << 16); }
__device__ __forceinline__ float bf_hi(uint32 u) { return __uint_as_float(u & 0xffff0000u); }

// Load an 8-bf16 MFMA fragment from LDS as 2x ds_read_b64 (8B-aligned, LDA=132)
__device__ __forceinline__ bf16x8 ld_frag8(const ushort16* p) {
    uint2 lo = *(const uint2*)p;
    uint2 hi = *(const uint2*)(p + 4);
    union { uint32 u[4]; bf16x8 v; } x;
    x.u[0] = lo.x; x.u[1] = lo.y; x.u[2] = hi.x; x.u[3] = hi.y;
    return x.v;
}

// ---------------------------------------------------------------------------
// bin_pass1: fixed-stride bucket scatter of PACKED edges (src:17|dst_loc:7).
// Proven two-phase form (LDS hist -> per-block base -> fine scatter).
// ---------------------------------------------------------------------------
__global__ __launch_bounds__(256) void bin_pass1_kernel(
        const int* __restrict__ ei, int* __restrict__ gcursor,
        uint32* __restrict__ staging) {
    __shared__ int hist[NBKT];
    __shared__ int base[NBKT];
    int tid = threadIdx.x;
    int e0 = blockIdx.x * BIN_CHUNK;

    for (int i = tid; i < NBKT; i += 256) hist[i] = 0;
    __syncthreads();

    #pragma unroll
    for (int k = 0; k < EPT; k++) {
        int e = e0 + k * 256 + tid;
        if (e < NE) {
            int d = ei[NE + e];
            atomicAdd(&hist[d >> BSH], 1);
        }
    }
    __syncthreads();

    for (int i = tid; i < NBKT; i += 256) {
        int c = hist[i];
        base[i] = c ? atomicAdd(&gcursor[i], c) : 0;
        hist[i] = 0;
    }
    __syncthreads();

    #pragma unroll
    for (int k = 0; k < EPT; k++) {
        int e = e0 + k * 256 + tid;
        if (e < NE) {
            int s = ei[e];
            int d = ei[NE + e];
            int b = d >> BSH;
            int off = atomicAdd(&hist[b], 1);
            staging[(size_t)b * CAP + base[b] + off] =
                ((uint32)s << 7) | (uint32)(d & 127);
        }
    }
}

// ---------------------------------------------------------------------------
// bucket_deg: per bucket, count in-degrees from staging -> dis = rsqrt(deg).
// ---------------------------------------------------------------------------
__global__ __launch_bounds__(256) void bucket_deg_kernel(
        const uint32* __restrict__ staging, const int* __restrict__ gcursor,
        float* __restrict__ dis) {
    __shared__ int cnt[1 << BSH];
    int b = blockIdx.x;
    int tid = threadIdx.x;
    int n = gcursor[b];

    if (tid < (1 << BSH)) cnt[tid] = 0;
    __syncthreads();
    for (int i = tid; i < n; i += 256)
        atomicAdd(&cnt[staging[(size_t)b * CAP + i] & 127u], 1);
    __syncthreads();
    if (tid < (1 << BSH)) {
        int node = (b << BSH) + tid;
        if (node < NN) dis[node] = (cnt[tid] > 0) ? rsqrtf((float)cnt[tid]) : 0.0f;
    }
}

// ---------------------------------------------------------------------------
// MFMA bf16 GEMM: out[M,N] = bf16(A[M,128] @ W[128,N])  (RAW -- no dis scale)
// BM=64, full K=128 resident in LDS, one barrier per block.
// ---------------------------------------------------------------------------
template <int N, bool ABF16>
__global__ __launch_bounds__(256) void gemm_mfma_kernel(
        const void* __restrict__ Ap, const float* __restrict__ W,
        ushort16* __restrict__ out, int M) {
    constexpr int BM = 64, K = K_DIM;
    constexpr int LDA = 132;
    constexpr int NT = N / 16;
    constexpr int NLOG = (N == 128) ? 7 : 6;

    __shared__ ushort16 As[BM * LDA];
    __shared__ ushort16 Bt[N * LDA];

    int tid = threadIdx.x;
    int row0 = blockIdx.x * BM;

    if constexpr (!ABF16) {
        const float* A = (const float*)Ap;
        #pragma unroll
        for (int c = 0; c < 8; c++) {
            int idx = c * 1024 + tid * 4;
            int r = idx >> 7, col = idx & 127;
            int ra = row0 + r;
            float4 v = (ra < M) ? *(const float4*)&A[(size_t)ra * K + col]
                                : make_float4(0.f, 0.f, 0.f, 0.f);
            ushort4 bq;
            bq.x = f2bf(v.x); bq.y = f2bf(v.y); bq.z = f2bf(v.z); bq.w = f2bf(v.w);
            *(ushort4*)&As[r * LDA + col] = bq;
        }
    } else {
        const ushort16* A = (const ushort16*)Ap;
        #pragma unroll
        for (int c = 0; c < 4; c++) {
            int idx = c * 2048 + tid * 8;
            int r = idx >> 7, col = idx & 127;
            int ra = row0 + r;
            uint4 v = make_uint4(0u, 0u, 0u, 0u);
            if (ra < M) v = *(const uint4*)&A[(size_t)ra * K + col];
            *(uint2*)&As[r * LDA + col]     = make_uint2(v.x, v.y);
            *(uint2*)&As[r * LDA + col + 4] = make_uint2(v.z, v.w);
        }
    }
    {
        #pragma unroll
        for (int c = 0; c < (K * N) / 1024; c++) {
            int idx = c * 1024 + tid * 4;
            int k = idx >> NLOG, n = idx & (N - 1);
            float4 v = *(const float4*)&W[idx];
            Bt[(n + 0) * LDA + k] = f2bf(v.x);
            Bt[(n + 1) * LDA + k] = f2bf(v.y);
            Bt[(n + 2) * LDA + k] = f2bf(v.z);
            Bt[(n + 3) * LDA + k] = f2bf(v.w);
        }
    }
    __syncthreads();

    int lane = tid & 63;
    int wv = tid >> 6;
    int m0 = wv * 16;
    int ml = lane & 15;
    int quad = lane >> 4;

    f32x4 acc[NT];
    #pragma unroll
    for (int i = 0; i < NT; i++) acc[i] = (f32x4){0.f, 0.f, 0.f, 0.f};

    #pragma unroll
    for (int ks = 0; ks < 4; ks++) {
        int kof = ks * 32 + quad * 8;
        bf16x8 a = ld_frag8(&As[(m0 + ml) * LDA + kof]);
        #pragma unroll
        for (int nt = 0; nt < NT; nt++) {
            bf16x8 bb = ld_frag8(&Bt[(nt * 16 + ml) * LDA + kof]);
            acc[nt] = __builtin_amdgcn_mfma_f32_16x16x32_bf16(a, bb, acc[nt], 0, 0, 0);
        }
    }

    #pragma unroll
    for (int r = 0; r < 4; r++) {
        int row = row0 + m0 + quad * 4 + r;
        if (row < M) {
            #pragma unroll
            for (int nt = 0; nt < NT; nt++)
                out[(size_t)row * N + nt * 16 + ml] = f2bf(acc[nt][r]);
        }
    }
}

// ---------------------------------------------------------------------------
// Bucket-mode aggregation, layer 1 (F=128): block = one 128-node dst bucket,
// 128x128 f32 accumulator in LDS (64 KB). Stream staged packed edges,
// gather g1[src] row (256B, 64 lanes x 4B), accumulate dis[src]*row into
// acc[dstloc] via LDS f32 atomics. Writeout: relu(dis[dst]*acc + b1) -> bf16.
// 8-deep edge pipelining per wave (8 gathers in flight).
// ---------------------------------------------------------------------------
__global__ __launch_bounds__(256) void agg128b_kernel(
        const ushort16* __restrict__ g1, const uint32* __restrict__ staging,
        const int* __restrict__ gcursor, const float* __restrict__ dis,
        const float* __restrict__ b1, ushort16* __restrict__ h) {
    __shared__ float acc[128 * 128];           // 64 KB
    int b = blockIdx.x;
    int tid = threadIdx.x;
    int lane = tid & 63, wv = tid >> 6;
    int n = gcursor[b];

    #pragma unroll
    for (int i = tid * 4; i < 128 * 128; i += 1024)
        *(float4*)&acc[i] = make_float4(0.f, 0.f, 0.f, 0.f);
    __syncthreads();

    int w0 = (int)(((long long)n * wv) >> 2);
    int w1 = (int)(((long long)n * (wv + 1)) >> 2);

    const char* gb = (const char*)g1;
    for (int base = w0; base < w1; base += 64) {
        int nk = w1 - base; if (nk > 64) nk = 64;
        uint32 pr = staging[(size_t)b * CAP + base + lane];   // +64 slack alloc'd
        int k = 0;
        for (; k + 8 <= nk; k += 8) {
            uint32 p[8], r[8]; float dsc[8];
            #pragma unroll
            for (int j = 0; j < 8; j++) p[j] = __shfl(pr, k + j);
            #pragma unroll
            for (int j = 0; j < 8; j++)
                r[j] = *(const uint32*)(gb + (((size_t)(p[j] >> 7)) << 8) + lane * 4);
            #pragma unroll
            for (int j = 0; j < 8; j++) dsc[j] = dis[p[j] >> 7];
            #pragma unroll
            for (int j = 0; j < 8; j++) {
                int nl = p[j] & 127;
                atomicAdd(&acc[nl * 128 + lane * 2],     bf_lo(r[j]) * dsc[j]);
                atomicAdd(&acc[nl * 128 + lane * 2 + 1], bf_hi(r[j]) * dsc[j]);
            }
        }
        for (; k < nk; k++) {
            uint32 p = __shfl(pr, k);
            uint32 r = *(const uint32*)(gb + (((size_t)(p >> 7)) << 8) + lane * 4);
            float d = dis[p >> 7];
            int nl = p & 127;
            atomicAdd(&acc[nl * 128 + lane * 2],     bf_lo(r) * d);
            atomicAdd(&acc[nl * 128 + lane * 2 + 1], bf_hi(r) * d);
        }
    }
    __syncthreads();

    // writeout: 2 threads per node, 64 feats each
    int nl = tid >> 1;
    int node = (b << BSH) + nl;
    if (node < NN) {
        float sd = dis[node];
        int f0 = (tid & 1) << 6;
        #pragma unroll
        for (int f = 0; f < 64; f += 8) {
            float4 bA = *(const float4*)&b1[f0 + f];
            float4 bB = *(const float4*)&b1[f0 + f + 4];
            const float* ap = &acc[nl * 128 + f0 + f];
            float o0 = fmaxf(ap[0] * sd + bA.x, 0.f);
            float o1 = fmaxf(ap[1] * sd + bA.y, 0.f);
            float o2 = fmaxf(ap[2] * sd + bA.z, 0.f);
            float o3 = fmaxf(ap[3] * sd + bA.w, 0.f);
            float o4 = fmaxf(ap[4] * sd + bB.x, 0.f);
            float o5 = fmaxf(ap[5] * sd + bB.y, 0.f);
            float o6 = fmaxf(ap[6] * sd + bB.z, 0.f);
            float o7 = fmaxf(ap[7] * sd + bB.w, 0.f);
            uint4 pk;
            pk.x = ((uint32)f2bf(o1) << 16) | (uint32)f2bf(o0);
            pk.y = ((uint32)f2bf(o3) << 16) | (uint32)f2bf(o2);
            pk.z = ((uint32)f2bf(o5) << 16) | (uint32)f2bf(o4);
            pk.w = ((uint32)f2bf(o7) << 16) | (uint32)f2bf(o6);
            *(uint4*)&h[(size_t)node * 128 + f0 + f] = pk;
        }
    }
}

// ---------------------------------------------------------------------------
// Bucket-mode aggregation, layer 2 (F=64): 128x64 f32 LDS acc (32 KB).
// Half-wave per edge (32 lanes x 4B = 128B row); 8 edges per half in flight.
// Writeout: dis[dst]*acc + b2 -> f32 out.
// ---------------------------------------------------------------------------
__global__ __launch_bounds__(256) void agg64b_kernel(
        const ushort16* __restrict__ g2, const uint32* __restrict__ staging,
        const int* __restrict__ gcursor, const float* __restrict__ dis,
        const float* __restrict__ b2, float* __restrict__ out) {
    __shared__ float acc[128 * 64];            // 32 KB
    int b = blockIdx.x;
    int tid = threadIdx.x;
    int lane = tid & 63, wv = tid >> 6;
    int half = lane >> 5, l2 = lane & 31;
    int n = gcursor[b];

    #pragma unroll
    for (int i = tid * 4; i < 128 * 64; i += 1024)
        *(float4*)&acc[i] = make_float4(0.f, 0.f, 0.f, 0.f);
    __syncthreads();

    int w0 = (int)(((long long)n * wv) >> 2);
    int w1 = (int)(((long long)n * (wv + 1)) >> 2);

    const char* gb = (const char*)g2;
    for (int base = w0; base < w1; base += 64) {
        int nk = w1 - base; if (nk > 64) nk = 64;
        uint32 pr = staging[(size_t)b * CAP + base + lane];   // +64 slack alloc'd
        int k = 0;
        for (; k + 16 <= nk; k += 16) {
            uint32 p[8], r[8]; float dsc[8];
            #pragma unroll
            for (int j = 0; j < 8; j++) p[j] = __shfl(pr, k + 2 * j + half);
            #pragma unroll
            for (int j = 0; j < 8; j++)
                r[j] = *(const uint32*)(gb + (((size_t)(p[j] >> 7)) << 7) + l2 * 4);
            #pragma unroll
            for (int j = 0; j < 8; j++) dsc[j] = dis[p[j] >> 7];
            #pragma unroll
            for (int j = 0; j < 8; j++) {
                int nl = p[j] & 127;
                atomicAdd(&acc[nl * 64 + l2 * 2],     bf_lo(r[j]) * dsc[j]);
                atomicAdd(&acc[nl * 64 + l2 * 2 + 1], bf_hi(r[j]) * dsc[j]);
            }
        }
        for (; k < nk; k += 2) {
            int e = k + half;
            bool ok = e < nk;
            uint32 p = __shfl(pr, e & 63);
            if (ok) {
                uint32 r = *(const uint32*)(gb + (((size_t)(p >> 7)) << 7) + l2 * 4);
                float d = dis[p >> 7];
                int nl = p & 127;
                atomicAdd(&acc[nl * 64 + l2 * 2],     bf_lo(r) * d);
                atomicAdd(&acc[nl * 64 + l2 * 2 + 1], bf_hi(r) * d);
            }
        }
    }
    __syncthreads();

    // writeout: 2 threads per node, 32 feats each
    int nl = tid >> 1;
    int node = (b << BSH) + nl;
    if (node < NN) {
        float sd = dis[node];
        int f0 = (tid & 1) << 5;
        #pragma unroll
        for (int f = 0; f < 32; f += 4) {
            float4 bb = *(const float4*)&b2[f0 + f];
            const float* ap = &acc[nl * 64 + f0 + f];
            float4 o = make_float4(ap[0] * sd + bb.x, ap[1] * sd + bb.y,
                                   ap[2] * sd + bb.z, ap[3] * sd + bb.w);
            *(float4*)&out[(size_t)node * 64 + f0 + f] = o;
        }
    }
}

// ---------------------------------------------------------------------------
// Launch.  Workspace: 0.4 (dis) + 8.0 (staging) + 25.6 (g1) + 25.6 (h)
// = 59.6 MB  (<= 62.1 MB proven-good footprint).
// staging lives to the end (both agg passes read it). g2 aliases g1.
// ---------------------------------------------------------------------------
extern "C" void kernel_launch(void* const* d_in, const int* in_sizes, int n_in,
                              void* d_out, int out_size, void* d_ws, size_t ws_size,
                              hipStream_t stream) {
    const float* x  = (const float*)d_in[0];
    const int*   ei = (const int*)d_in[1];
    const float* W1 = (const float*)d_in[2];
    const float* b1 = (const float*)d_in[3];
    const float* W2 = (const float*)d_in[4];
    const float* b2 = (const float*)d_in[5];
    float* out = (float*)d_out;

    char* ws = (char*)d_ws;
    size_t off = 0;
    auto alloc = [&](size_t bytes) {
        void* p = ws + off;
        off = (off + bytes + 255) & ~(size_t)255;
        return p;
    };

    int*      gcursor = (int*)alloc(NBKT * 4);
    float*    dis     = (float*)alloc(NN * 4);
    uint32*   staging = (uint32*)alloc(((size_t)NBKT * CAP + 64) * 4);  // +64 slack
    ushort16* g1      = (ushort16*)alloc((size_t)NN * 128 * 2);         // 25.6 MB
    ushort16* h       = (ushort16*)alloc((size_t)NN * 128 * 2);         // 25.6 MB
    ushort16* g2      = g1;               // alias: g1 dead after agg128b

    hipMemsetAsync(gcursor, 0, NBKT * 4, stream);

    bin_pass1_kernel<<<(NE + BIN_CHUNK - 1) / BIN_CHUNK, 256, 0, stream>>>(
        ei, gcursor, staging);
    bucket_deg_kernel<<<NBKT, 256, 0, stream>>>(staging, gcursor, dis);

    const int GEMM_BLOCKS = (NN + 63) / 64;   // 1563
    gemm_mfma_kernel<128, false><<<GEMM_BLOCKS, 256, 0, stream>>>(x, W1, g1, NN);

    agg128b_kernel<<<NBKT, 256, 0, stream>>>(g1, staging, gcursor, dis, b1, h);

    gemm_mfma_kernel<64, true><<<GEMM_BLOCKS, 256, 0, stream>>>(h, W2, g2, NN);

    agg64b_kernel<<<NBKT, 256, 0, stream>>>(g2, staging, gcursor, dis, b2, out);
}

// Round 11
// 265.241 us; speedup vs baseline: 8.3287x; 8.3287x over previous
//
#include <hip/hip_runtime.h>
#include <stdint.h>

// Problem constants (fixed by reference)
#define NN 100000      // nodes
#define NE 1600000     // edges
#define K_DIM 128      // IN_DIM == HID_DIM

// Coarse binning for CSR build
#define BSH 7                                   // 128 nodes per bucket
#define NBKT ((NN + (1 << BSH) - 1) >> BSH)     // 782 buckets
#define EPT 32                                  // edges per thread, pass 1
#define BIN_CHUNK (256 * EPT)                   // 8192 edges per block
#define BIN_BLOCKS ((NE + BIN_CHUNK - 1) / BIN_CHUNK)   // 196
#define CAP 4096                                // staging capacity per bucket
#define PADE 2301000                            // padded edge capacity (+ slack)

typedef unsigned int uint32;
typedef unsigned short ushort16;
typedef __attribute__((ext_vector_type(8))) short bf16x8;
typedef __attribute__((ext_vector_type(4))) float f32x4;

__device__ __forceinline__ ushort16 f2bf(float f) {
    uint32 u = __float_as_uint(f);
    u += 0x7fffu + ((u >> 16) & 1u);   // round-to-nearest-even
    return (ushort16)(u >> 16);
}
__device__ __forceinline__ float bf_lo(uint32 u) { return __uint_as_float(u << 16); }
__device__ __forceinline__ float bf_hi(uint32 u) { return __uint_as_float(u & 0xffff0000u); }

// Accumulate 8 bf16 pairs from a uint4 into a0..a7 (unscaled)
#define ACC8(v) do { \
    a0 += bf_lo((v).x); a1 += bf_hi((v).x); \
    a2 += bf_lo((v).y); a3 += bf_hi((v).y); \
    a4 += bf_lo((v).z); a5 += bf_hi((v).z); \
    a6 += bf_lo((v).w); a7 += bf_hi((v).w); } while (0)

// Scaled accumulate: a += d * row (fma)
#define ACC8S(v,d) do { \
    a0 = fmaf(d, bf_lo((v).x), a0); a1 = fmaf(d, bf_hi((v).x), a1); \
    a2 = fmaf(d, bf_lo((v).y), a2); a3 = fmaf(d, bf_hi((v).y), a3); \
    a4 = fmaf(d, bf_lo((v).z), a4); a5 = fmaf(d, bf_hi((v).z), a5); \
    a6 = fmaf(d, bf_lo((v).w), a6); a7 = fmaf(d, bf_hi((v).w), a7); } while (0)

// Load an 8-bf16 MFMA fragment from LDS as 2x ds_read_b64 (8B-aligned, LDA=132)
__device__ __forceinline__ bf16x8 ld_frag8(const ushort16* p) {
    uint2 lo = *(const uint2*)p;
    uint2 hi = *(const uint2*)(p + 4);
    union { uint32 u[4]; bf16x8 v; } x;
    x.u[0] = lo.x; x.u[1] = lo.y; x.u[2] = hi.x; x.u[3] = hi.y;
    return x.v;
}

// ---------------------------------------------------------------------------
// MEGA kernel: blocks [0, BIN_BLOCKS) run the CSR binning pass (depends only
// on ei); the rest run the layer-1 GEMM (depends only on x, W1). Independent
// work co-resident on the machine -- bin's atomic/latency time hides under
// gemm's MFMA/BW time. GEMM output is RAW (dis[src] moved into agg128).
// ---------------------------------------------------------------------------
__global__ __launch_bounds__(256) void binxgemm_kernel(
        const int* __restrict__ ei, int* __restrict__ gcursor,
        uint32* __restrict__ staging,
        const float* __restrict__ x, const float* __restrict__ W1,
        ushort16* __restrict__ g1, int M) {
    __shared__ __align__(16) char smem[50688];   // max(bin 6256, gemm 50688)
    int tid = threadIdx.x;

    if (blockIdx.x < BIN_BLOCKS) {
        // ---------------- bin body (R8-proven two-phase scatter) ----------
        int* hist = (int*)smem;
        int* base = hist + NBKT;
        int e0 = blockIdx.x * BIN_CHUNK;

        for (int i = tid; i < NBKT; i += 256) hist[i] = 0;
        __syncthreads();

        #pragma unroll
        for (int k = 0; k < EPT; k++) {
            int e = e0 + k * 256 + tid;
            if (e < NE) {
                int d = ei[NE + e];
                atomicAdd(&hist[d >> BSH], 1);
            }
        }
        __syncthreads();

        for (int i = tid; i < NBKT; i += 256) {
            int c = hist[i];
            base[i] = c ? atomicAdd(&gcursor[i], c) : 0;
            hist[i] = 0;
        }
        __syncthreads();

        #pragma unroll
        for (int k = 0; k < EPT; k++) {
            int e = e0 + k * 256 + tid;
            if (e < NE) {
                int s = ei[e];
                int d = ei[NE + e];
                int b = d >> BSH;
                int off = atomicAdd(&hist[b], 1);
                staging[(size_t)b * CAP + base[b] + off] =
                    ((uint32)s << 7) | (uint32)(d & 127);
            }
        }
    } else {
        // ---------------- gemm body: g1 = bf16(x @ W1), raw --------------
        constexpr int N = 128, BM = 64, K = K_DIM, LDA = 132, NT = N / 16;
        ushort16* As = (ushort16*)smem;          // 64*132
        ushort16* Bt = As + BM * LDA;            // 128*132
        int bid = (int)blockIdx.x - BIN_BLOCKS;
        int row0 = bid * BM;

        if (bid == 0 && tid < 64)                // zero dummy row NN (256 B)
            ((uint32*)&g1[(size_t)NN * N])[tid] = 0u;

        #pragma unroll
        for (int c = 0; c < 8; c++) {
            int idx = c * 1024 + tid * 4;
            int r = idx >> 7, col = idx & 127;
            int ra = row0 + r;
            float4 v = (ra < M) ? *(const float4*)&x[(size_t)ra * K + col]
                                : make_float4(0.f, 0.f, 0.f, 0.f);
            ushort4 bq;
            bq.x = f2bf(v.x); bq.y = f2bf(v.y); bq.z = f2bf(v.z); bq.w = f2bf(v.w);
            *(ushort4*)&As[r * LDA + col] = bq;
        }
        #pragma unroll
        for (int c = 0; c < (K * N) / 1024; c++) {
            int idx = c * 1024 + tid * 4;
            int k = idx >> 7, n = idx & (N - 1);
            float4 v = *(const float4*)&W1[idx];
            Bt[(n + 0) * LDA + k] = f2bf(v.x);
            Bt[(n + 1) * LDA + k] = f2bf(v.y);
            Bt[(n + 2) * LDA + k] = f2bf(v.z);
            Bt[(n + 3) * LDA + k] = f2bf(v.w);
        }
        __syncthreads();

        int lane = tid & 63;
        int wv = tid >> 6;
        int m0 = wv * 16;
        int ml = lane & 15;
        int quad = lane >> 4;

        f32x4 acc[NT];
        #pragma unroll
        for (int i = 0; i < NT; i++) acc[i] = (f32x4){0.f, 0.f, 0.f, 0.f};

        #pragma unroll
        for (int ks = 0; ks < 4; ks++) {
            int kof = ks * 32 + quad * 8;
            bf16x8 a = ld_frag8(&As[(m0 + ml) * LDA + kof]);
            #pragma unroll
            for (int nt = 0; nt < NT; nt++) {
                bf16x8 bb = ld_frag8(&Bt[(nt * 16 + ml) * LDA + kof]);
                acc[nt] = __builtin_amdgcn_mfma_f32_16x16x32_bf16(a, bb, acc[nt], 0, 0, 0);
            }
        }

        #pragma unroll
        for (int r = 0; r < 4; r++) {
            int row = row0 + m0 + quad * 4 + r;
            if (row < M) {
                #pragma unroll
                for (int nt = 0; nt < NT; nt++)
                    g1[(size_t)row * N + nt * 16 + ml] = f2bf(acc[nt][r]);
            }
        }
    }
}

// ---------------------------------------------------------------------------
// bucket_finish: per bucket -- staged edges -> LDS (one read), LDS degree
// count, local scan, ONE global atomicAdd to allocate the bucket's compact
// ssrc region, fine scatter + pad fill. Also writes dis[NN] = 0 (dummy node).
// ---------------------------------------------------------------------------
__global__ __launch_bounds__(256) void bucket_finish_kernel(
        const uint32* __restrict__ staging, const int* __restrict__ gcursor,
        int* __restrict__ gedge, int* __restrict__ deg, float* __restrict__ dis,
        int* __restrict__ row_start, int* __restrict__ ssrc) {
    __shared__ uint32 pairs[CAP];        // 16 KB
    __shared__ int cnt[1 << BSH];
    __shared__ int sb[1 << BSH];
    __shared__ int cur[1 << BSH];
    __shared__ int pend[1 << BSH];
    __shared__ int bbase;
    int b = blockIdx.x;
    int node0 = b << BSH;
    int tid = threadIdx.x;
    int n_edges = gcursor[b];

    if (tid < (1 << BSH)) cnt[tid] = 0;
    __syncthreads();

    for (int i = tid; i < n_edges; i += 256) {
        uint32 p = staging[(size_t)b * CAP + i];
        pairs[i] = p;
        atomicAdd(&cnt[p & 127u], 1);
    }
    __syncthreads();

    int p = 0;
    if (tid < (1 << BSH)) {
        int node = node0 + tid;
        int c = cnt[tid];
        if (node < NN) {
            deg[node] = c;
            dis[node] = (c > 0) ? rsqrtf((float)c) : 0.0f;
            p = (c + 7) & ~7;
        } else if (node == NN) {
            dis[NN] = 0.0f;              // dummy node scale (finite, zero)
        }
        sb[tid] = p;
    }
    __syncthreads();
    #pragma unroll
    for (int off = 1; off < (1 << BSH); off <<= 1) {
        int t = (tid >= off && tid < (1 << BSH)) ? sb[tid - off] : 0;
        __syncthreads();
        if (tid < (1 << BSH)) sb[tid] += t;
        __syncthreads();
    }
    if (tid == (1 << BSH) - 1) bbase = atomicAdd(gedge, sb[tid]);
    __syncthreads();

    if (tid < (1 << BSH)) {
        int rs = bbase + sb[tid] - p;    // exclusive
        cur[tid] = rs;
        pend[tid] = rs + p;
        int node = node0 + tid;
        if (node < NN) row_start[node] = rs;
    }
    __syncthreads();

    for (int i = tid; i < n_edges; i += 256) {
        uint32 pr = pairs[i];
        int off = atomicAdd(&cur[pr & 127u], 1);
        ssrc[off] = (int)(pr >> 7);
    }
    __syncthreads();

    if (tid < (1 << BSH)) {
        int node = node0 + tid;
        if (node < NN) {
            for (int q = cur[tid]; q < pend[tid]; q++) ssrc[q] = NN;   // dummy -> zero row
        }
    }
}

// ---------------------------------------------------------------------------
// MFMA bf16 GEMM (layer 2): g2 = bf16( dis[row] * (h @ W2) )
// h is bf16 (bias+relu already applied by agg128).
// ZROWB: block 0 zeroes ZROWB bytes at row NN of out.
// ---------------------------------------------------------------------------
template <int N, int ZROWB>
__global__ __launch_bounds__(256) void gemm_mfma_kernel(
        const ushort16* __restrict__ A, const float* __restrict__ W,
        const float* __restrict__ dis, ushort16* __restrict__ out, int M) {
    constexpr int BM = 64, K = K_DIM;
    constexpr int LDA = 132;
    constexpr int NT = N / 16;
    constexpr int NLOG = (N == 128) ? 7 : 6;

    __shared__ ushort16 As[BM * LDA];
    __shared__ ushort16 Bt[N * LDA];

    int tid = threadIdx.x;
    int row0 = blockIdx.x * BM;

    if constexpr (ZROWB > 0) {
        if (blockIdx.x == 0 && tid < ZROWB / 4)
            ((uint32*)&out[(size_t)NN * N])[tid] = 0u;
    }

    #pragma unroll
    for (int c = 0; c < 4; c++) {
        int idx = c * 2048 + tid * 8;
        int r = idx >> 7, col = idx & 127;
        int ra = row0 + r;
        uint4 v = make_uint4(0u, 0u, 0u, 0u);
        if (ra < M) v = *(const uint4*)&A[(size_t)ra * K + col];
        *(uint2*)&As[r * LDA + col]     = make_uint2(v.x, v.y);
        *(uint2*)&As[r * LDA + col + 4] = make_uint2(v.z, v.w);
    }
    {
        #pragma unroll
        for (int c = 0; c < (K * N) / 1024; c++) {
            int idx = c * 1024 + tid * 4;
            int k = idx >> NLOG, n = idx & (N - 1);
            float4 v = *(const float4*)&W[idx];
            Bt[(n + 0) * LDA + k] = f2bf(v.x);
            Bt[(n + 1) * LDA + k] = f2bf(v.y);
            Bt[(n + 2) * LDA + k] = f2bf(v.z);
            Bt[(n + 3) * LDA + k] = f2bf(v.w);
        }
    }
    __syncthreads();

    int lane = tid & 63;
    int wv = tid >> 6;
    int m0 = wv * 16;
    int ml = lane & 15;
    int quad = lane >> 4;

    f32x4 acc[NT];
    #pragma unroll
    for (int i = 0; i < NT; i++) acc[i] = (f32x4){0.f, 0.f, 0.f, 0.f};

    #pragma unroll
    for (int ks = 0; ks < 4; ks++) {
        int kof = ks * 32 + quad * 8;
        bf16x8 a = ld_frag8(&As[(m0 + ml) * LDA + kof]);
        #pragma unroll
        for (int nt = 0; nt < NT; nt++) {
            bf16x8 bb = ld_frag8(&Bt[(nt * 16 + ml) * LDA + kof]);
            acc[nt] = __builtin_amdgcn_mfma_f32_16x16x32_bf16(a, bb, acc[nt], 0, 0, 0);
        }
    }

    #pragma unroll
    for (int r = 0; r < 4; r++) {
        int row = row0 + m0 + quad * 4 + r;
        if (row < M) {
            float s = dis[row];
            #pragma unroll
            for (int nt = 0; nt < NT; nt++)
                out[(size_t)row * N + nt * 16 + ml] = f2bf(acc[nt][r] * s);
        }
    }
}

// ---------------------------------------------------------------------------
// Aggregation layer 1: F=128, bf16 gather -> bf16 out with ReLU.
// One wave per node; preload 64 edge indices AND their dis[src] scales,
// then 2-batch unrolled gather with per-edge fma scaling.
// ---------------------------------------------------------------------------
__global__ __launch_bounds__(256) void agg128_kernel(
        const ushort16* __restrict__ g, const int* __restrict__ row_start,
        const int* __restrict__ deg, const int* __restrict__ ssrc,
        const float* __restrict__ dis, const float* __restrict__ bias,
        ushort16* __restrict__ out) {
    int wave = (blockIdx.x * 256 + threadIdx.x) >> 6;
    int lane = threadIdx.x & 63;
    if (wave >= NN) return;

    int beg = row_start[wave];
    int ecount = (deg[wave] + 7) & ~7;   // padded degree
    float sc = dis[wave];

    int fl = lane & 15;            // feature octet: feats fl*8..fl*8+7
    int q  = lane >> 4;            // edge sub-slot 0..3
    int laneoff = fl * 16;         // byte offset within a 256B row

    // Preload 64 indices + scales. Clamp index for dis load: lanes past the
    // final row's end may read uninitialized ssrc (memory-safe, value-garbage,
    // never shfl-sourced) -- clamp keeps the dis gather in-bounds.
    int idx = ssrc[beg + lane];
    uint32 ci = (uint32)idx; if (ci > (uint32)NN) ci = NN;
    float dsv = dis[ci];

    float a0 = 0.f, a1 = 0.f, a2 = 0.f, a3 = 0.f;
    float a4 = 0.f, a5 = 0.f, a6 = 0.f, a7 = 0.f;

    const char* gb = (const char*)g;
    int nb = ((ecount < 64) ? ecount : 64) >> 3;   // batches covered by preload
    int b = 0;
    for (; b + 2 <= nb; b += 2) {
        int s0a = __shfl(idx, b * 8 + q);
        int s1a = __shfl(idx, b * 8 + 4 + q);
        int s0b = __shfl(idx, b * 8 + 8 + q);
        int s1b = __shfl(idx, b * 8 + 12 + q);
        float d0a = __shfl(dsv, b * 8 + q);
        float d1a = __shfl(dsv, b * 8 + 4 + q);
        float d0b = __shfl(dsv, b * 8 + 8 + q);
        float d1b = __shfl(dsv, b * 8 + 12 + q);
        uint4 v0a = *(const uint4*)(gb + (((uint32)s0a << 8) + laneoff));
        uint4 v1a = *(const uint4*)(gb + (((uint32)s1a << 8) + laneoff));
        uint4 v0b = *(const uint4*)(gb + (((uint32)s0b << 8) + laneoff));
        uint4 v1b = *(const uint4*)(gb + (((uint32)s1b << 8) + laneoff));
        ACC8S(v0a, d0a); ACC8S(v1a, d1a); ACC8S(v0b, d0b); ACC8S(v1b, d1b);
    }
    if (b < nb) {
        int s0 = __shfl(idx, b * 8 + q);
        int s1 = __shfl(idx, b * 8 + 4 + q);
        float d0 = __shfl(dsv, b * 8 + q);
        float d1 = __shfl(dsv, b * 8 + 4 + q);
        uint4 v0 = *(const uint4*)(gb + (((uint32)s0 << 8) + laneoff));
        uint4 v1 = *(const uint4*)(gb + (((uint32)s1 << 8) + laneoff));
        ACC8S(v0, d0); ACC8S(v1, d1);
    }
    // Rare tail: rows with more than 64 edges (values always valid: <= NN).
    for (int e = beg + 64; e < beg + ecount; e += 8) {
        int idx2 = ssrc[e + (lane & 7)];
        float dsv2 = dis[idx2];
        int s0 = __shfl(idx2, q);
        int s1 = __shfl(idx2, 4 + q);
        float d0 = __shfl(dsv2, q);
        float d1 = __shfl(dsv2, 4 + q);
        uint4 v0 = *(const uint4*)(gb + (((uint32)s0 << 8) + laneoff));
        uint4 v1 = *(const uint4*)(gb + (((uint32)s1 << 8) + laneoff));
        ACC8S(v0, d0); ACC8S(v1, d1);
    }

    // combine the 4 quad partial sums (tree)
    a0 += __shfl_xor(a0, 16); a1 += __shfl_xor(a1, 16);
    a2 += __shfl_xor(a2, 16); a3 += __shfl_xor(a3, 16);
    a4 += __shfl_xor(a4, 16); a5 += __shfl_xor(a5, 16);
    a6 += __shfl_xor(a6, 16); a7 += __shfl_xor(a7, 16);
    a0 += __shfl_xor(a0, 32); a1 += __shfl_xor(a1, 32);
    a2 += __shfl_xor(a2, 32); a3 += __shfl_xor(a3, 32);
    a4 += __shfl_xor(a4, 32); a5 += __shfl_xor(a5, 32);
    a6 += __shfl_xor(a6, 32); a7 += __shfl_xor(a7, 32);

    if (lane < 16) {
        float4 bA = *(const float4*)&bias[fl * 8];
        float4 bB = *(const float4*)&bias[fl * 8 + 4];
        float o0 = fmaxf(sc * a0 + bA.x, 0.f);
        float o1 = fmaxf(sc * a1 + bA.y, 0.f);
        float o2 = fmaxf(sc * a2 + bA.z, 0.f);
        float o3 = fmaxf(sc * a3 + bA.w, 0.f);
        float o4 = fmaxf(sc * a4 + bB.x, 0.f);
        float o5 = fmaxf(sc * a5 + bB.y, 0.f);
        float o6 = fmaxf(sc * a6 + bB.z, 0.f);
        float o7 = fmaxf(sc * a7 + bB.w, 0.f);
        uint4 pk;
        pk.x = ((uint32)f2bf(o1) << 16) | (uint32)f2bf(o0);
        pk.y = ((uint32)f2bf(o3) << 16) | (uint32)f2bf(o2);
        pk.z = ((uint32)f2bf(o5) << 16) | (uint32)f2bf(o4);
        pk.w = ((uint32)f2bf(o7) << 16) | (uint32)f2bf(o6);
        *(uint4*)&out[(size_t)wave * 128 + fl * 8] = pk;
    }
}

// ---------------------------------------------------------------------------
// Aggregation layer 2: F=64, bf16 gather -> f32 out (no activation).
// Half-wave per node (unchanged R8 form; g2 carries dis scaling from gemm64).
// ---------------------------------------------------------------------------
__global__ __launch_bounds__(256) void agg64_kernel(
        const ushort16* __restrict__ g, const int* __restrict__ row_start,
        const int* __restrict__ deg, const int* __restrict__ ssrc,
        const float* __restrict__ dis, const float* __restrict__ bias,
        float* __restrict__ out) {
    int wave = (blockIdx.x * 256 + threadIdx.x) >> 6;
    int lane = threadIdx.x & 63;
    int half = lane >> 5;
    int l2 = lane & 31;
    int node = wave * 2 + half;          // NN even => both halves valid
    if (node >= NN) return;

    int beg = row_start[node];
    int ecount = (deg[node] + 7) & ~7;   // padded degree
    float sc = dis[node];

    int fl = l2 & 7;               // feature octet: feats fl*8..fl*8+7
    int q  = l2 >> 3;              // edge sub-slot 0..3
    int laneoff = fl * 16;         // byte offset within a 128B row

    int idx = ssrc[beg + l2];

    float a0 = 0.f, a1 = 0.f, a2 = 0.f, a3 = 0.f;
    float a4 = 0.f, a5 = 0.f, a6 = 0.f, a7 = 0.f;

    const char* gb = (const char*)g;
    int nb = ((ecount < 32) ? ecount : 32) >> 3;
    int b = 0;
    for (; b + 2 <= nb; b += 2) {
        int s0a = __shfl(idx, half * 32 + b * 8 + q);
        int s1a = __shfl(idx, half * 32 + b * 8 + 4 + q);
        int s0b = __shfl(idx, half * 32 + b * 8 + 8 + q);
        int s1b = __shfl(idx, half * 32 + b * 8 + 12 + q);
        uint4 v0a = *(const uint4*)(gb + (((uint32)s0a << 7) + laneoff));
        uint4 v1a = *(const uint4*)(gb + (((uint32)s1a << 7) + laneoff));
        uint4 v0b = *(const uint4*)(gb + (((uint32)s0b << 7) + laneoff));
        uint4 v1b = *(const uint4*)(gb + (((uint32)s1b << 7) + laneoff));
        ACC8(v0a); ACC8(v1a); ACC8(v0b); ACC8(v1b);
    }
    if (b < nb) {
        int s0 = __shfl(idx, half * 32 + b * 8 + q);
        int s1 = __shfl(idx, half * 32 + b * 8 + 4 + q);
        uint4 v0 = *(const uint4*)(gb + (((uint32)s0 << 7) + laneoff));
        uint4 v1 = *(const uint4*)(gb + (((uint32)s1 << 7) + laneoff));
        ACC8(v0); ACC8(v1);
    }
    for (int e = beg + 32; e < beg + ecount; e += 8) {
        int idx2 = ssrc[e + (l2 & 7)];
        int s0 = __shfl(idx2, half * 32 + q);
        int s1 = __shfl(idx2, half * 32 + 4 + q);
        uint4 v0 = *(const uint4*)(gb + (((uint32)s0 << 7) + laneoff));
        uint4 v1 = *(const uint4*)(gb + (((uint32)s1 << 7) + laneoff));
        ACC8(v0); ACC8(v1);
    }

    a0 += __shfl_xor(a0, 8);  a1 += __shfl_xor(a1, 8);
    a2 += __shfl_xor(a2, 8);  a3 += __shfl_xor(a3, 8);
    a4 += __shfl_xor(a4, 8);  a5 += __shfl_xor(a5, 8);
    a6 += __shfl_xor(a6, 8);  a7 += __shfl_xor(a7, 8);
    a0 += __shfl_xor(a0, 16); a1 += __shfl_xor(a1, 16);
    a2 += __shfl_xor(a2, 16); a3 += __shfl_xor(a3, 16);
    a4 += __shfl_xor(a4, 16); a5 += __shfl_xor(a5, 16);
    a6 += __shfl_xor(a6, 16); a7 += __shfl_xor(a7, 16);

    if (l2 < 8) {
        float4 bA = *(const float4*)&bias[fl * 8];
        float4 bB = *(const float4*)&bias[fl * 8 + 4];
        float4 oA = make_float4(sc * a0 + bA.x, sc * a1 + bA.y,
                                sc * a2 + bA.z, sc * a3 + bA.w);
        float4 oB = make_float4(sc * a4 + bB.x, sc * a5 + bB.y,
                                sc * a6 + bB.z, sc * a7 + bB.w);
        *(float4*)&out[(size_t)node * 64 + fl * 8]     = oA;
        *(float4*)&out[(size_t)node * 64 + fl * 8 + 4] = oB;
    }
}

// ---------------------------------------------------------------------------
// Launch. Workspace ~61.7 MB (<= proven 62.1). staging coexists with g1
// (mega kernel writes both), so staging shares the h region instead:
// staging dead after bucket_finish; h written first by agg128.
// ---------------------------------------------------------------------------
extern "C" void kernel_launch(void* const* d_in, const int* in_sizes, int n_in,
                              void* d_out, int out_size, void* d_ws, size_t ws_size,
                              hipStream_t stream) {
    const float* x  = (const float*)d_in[0];
    const int*   ei = (const int*)d_in[1];
    const float* W1 = (const float*)d_in[2];
    const float* b1 = (const float*)d_in[3];
    const float* W2 = (const float*)d_in[4];
    const float* b2 = (const float*)d_in[5];
    float* out = (float*)d_out;

    char* ws = (char*)d_ws;
    size_t off = 0;
    auto alloc = [&](size_t bytes) {
        void* p = ws + off;
        off = (off + bytes + 255) & ~(size_t)255;
        return p;
    };

    int*      deg_i      = (int*)alloc(NN * 4);
    float*    dis        = (float*)alloc((NN + 1) * 4);   // +1: dis[NN] = 0
    int*      row_start  = (int*)alloc(NN * 4);
    int*      gcursor    = (int*)alloc((NBKT + 1) * 4);   // +1: gedge cursor
    int*      ssrc       = (int*)alloc((size_t)PADE * 4); // 9.2 MB
    ushort16* g1         = (ushort16*)alloc((size_t)(NN + 1) * 128 * 2);  // 25.6 MB
    // staging (12.8 MB) and h (25.6 MB) share one region: staging dead after
    // bucket_finish; h written first by agg128 (after bucket_finish).
    char*     big        = (char*)alloc((size_t)NN * 128 * 2);
    uint32*   staging    = (uint32*)big;
    ushort16* h          = (ushort16*)big;
    ushort16* g2         = g1;               // alias: g1 dead after agg128
    int*      gedge      = gcursor + NBKT;

    hipMemsetAsync(gcursor, 0, (NBKT + 1) * 4, stream);

    // [CSR binning  ||  layer-1 GEMM] in one launch (independent inputs)
    binxgemm_kernel<<<BIN_BLOCKS + (NN + 63) / 64, 256, 0, stream>>>(
        ei, gcursor, staging, x, W1, g1, NN);

    bucket_finish_kernel<<<NBKT, 256, 0, stream>>>(
        staging, gcursor, gedge, deg_i, dis, row_start, ssrc);

    const int AGG_BLOCKS = (NN + 3) / 4;      // 25000 (4 waves/block)
    agg128_kernel<<<AGG_BLOCKS, 256, 0, stream>>>(g1, row_start, deg_i, ssrc, dis, b1, h);

    const int GEMM_BLOCKS = (NN + 63) / 64;   // 1563
    gemm_mfma_kernel<64, 128><<<GEMM_BLOCKS, 256, 0, stream>>>(h, W2, dis, g2, NN);

    const int AGG2_BLOCKS = (NN / 2 + 3) / 4; // 12500 (half-wave per node)
    agg64_kernel<<<AGG2_BLOCKS, 256, 0, stream>>>(g2, row_start, deg_i, ssrc, dis, b2, out);
}

// Round 12
// 261.975 us; speedup vs baseline: 8.4325x; 1.0125x over previous
//
#include <hip/hip_runtime.h>
#include <stdint.h>

// Problem constants (fixed by reference)
#define NN 100000      // nodes
#define NE 1600000     // edges
#define K_DIM 128      // IN_DIM == HID_DIM

// Coarse binning for CSR build
#define BSH 7                                   // 128 nodes per bucket
#define NBKT ((NN + (1 << BSH) - 1) >> BSH)     // 782 buckets
#define EPT 32                                  // edges per thread, pass 1
#define BIN_CHUNK (256 * EPT)                   // 8192 edges per block
#define BIN_BLOCKS ((NE + BIN_CHUNK - 1) / BIN_CHUNK)   // 196
#define CAP 4096                                // staging capacity per bucket
#define PADE 2301000                            // padded edge capacity (+ slack)

typedef unsigned int uint32;
typedef unsigned short ushort16;
typedef __attribute__((ext_vector_type(8))) short bf16x8;
typedef __attribute__((ext_vector_type(4))) float f32x4;

__device__ __forceinline__ ushort16 f2bf(float f) {
    uint32 u = __float_as_uint(f);
    u += 0x7fffu + ((u >> 16) & 1u);   // round-to-nearest-even
    return (ushort16)(u >> 16);
}
__device__ __forceinline__ float bf_lo(uint32 u) { return __uint_as_float(u << 16); }
__device__ __forceinline__ float bf_hi(uint32 u) { return __uint_as_float(u & 0xffff0000u); }

// Accumulate 8 bf16 pairs from a uint4 into a0..a7 (unscaled)
#define ACC8(v) do { \
    a0 += bf_lo((v).x); a1 += bf_hi((v).x); \
    a2 += bf_lo((v).y); a3 += bf_hi((v).y); \
    a4 += bf_lo((v).z); a5 += bf_hi((v).z); \
    a6 += bf_lo((v).w); a7 += bf_hi((v).w); } while (0)

// Scaled accumulate: a += d * row (fma)
#define ACC8S(v,d) do { \
    a0 = fmaf(d, bf_lo((v).x), a0); a1 = fmaf(d, bf_hi((v).x), a1); \
    a2 = fmaf(d, bf_lo((v).y), a2); a3 = fmaf(d, bf_hi((v).y), a3); \
    a4 = fmaf(d, bf_lo((v).z), a4); a5 = fmaf(d, bf_hi((v).z), a5); \
    a6 = fmaf(d, bf_lo((v).w), a6); a7 = fmaf(d, bf_hi((v).w), a7); } while (0)

// Load an 8-bf16 MFMA fragment from LDS as 2x ds_read_b64 (8B-aligned, LDA=132)
__device__ __forceinline__ bf16x8 ld_frag8(const ushort16* p) {
    uint2 lo = *(const uint2*)p;
    uint2 hi = *(const uint2*)(p + 4);
    union { uint32 u[4]; bf16x8 v; } x;
    x.u[0] = lo.x; x.u[1] = lo.y; x.u[2] = hi.x; x.u[3] = hi.y;
    return x.v;
}

// ---------------------------------------------------------------------------
// MEGA kernel: blocks [0, BIN_BLOCKS) run the CSR binning pass (depends only
// on ei); the rest run the layer-1 GEMM (depends only on x, W1). Independent
// work co-resident -- bin's atomic/latency time hides under gemm's MFMA/BW.
// GEMM output is RAW (dis[src] applied per-edge in agg128f).
// ---------------------------------------------------------------------------
__global__ __launch_bounds__(256) void binxgemm_kernel(
        const int* __restrict__ ei, int* __restrict__ gcursor,
        uint32* __restrict__ staging,
        const float* __restrict__ x, const float* __restrict__ W1,
        ushort16* __restrict__ g1, int M) {
    __shared__ __align__(16) char smem[50688];   // max(bin 6256, gemm 50688)
    int tid = threadIdx.x;

    if (blockIdx.x < BIN_BLOCKS) {
        // ---------------- bin body (R8-proven two-phase scatter) ----------
        int* hist = (int*)smem;
        int* base = hist + NBKT;
        int e0 = blockIdx.x * BIN_CHUNK;

        for (int i = tid; i < NBKT; i += 256) hist[i] = 0;
        __syncthreads();

        #pragma unroll
        for (int k = 0; k < EPT; k++) {
            int e = e0 + k * 256 + tid;
            if (e < NE) {
                int d = ei[NE + e];
                atomicAdd(&hist[d >> BSH], 1);
            }
        }
        __syncthreads();

        for (int i = tid; i < NBKT; i += 256) {
            int c = hist[i];
            base[i] = c ? atomicAdd(&gcursor[i], c) : 0;
            hist[i] = 0;
        }
        __syncthreads();

        #pragma unroll
        for (int k = 0; k < EPT; k++) {
            int e = e0 + k * 256 + tid;
            if (e < NE) {
                int s = ei[e];
                int d = ei[NE + e];
                int b = d >> BSH;
                int off = atomicAdd(&hist[b], 1);
                staging[(size_t)b * CAP + base[b] + off] =
                    ((uint32)s << 7) | (uint32)(d & 127);
            }
        }
    } else {
        // ---------------- gemm body: g1 = bf16(x @ W1), raw --------------
        constexpr int N = 128, BM = 64, K = K_DIM, LDA = 132, NT = N / 16;
        ushort16* As = (ushort16*)smem;          // 64*132
        ushort16* Bt = As + BM * LDA;            // 128*132
        int bid = (int)blockIdx.x - BIN_BLOCKS;
        int row0 = bid * BM;

        if (bid == 0 && tid < 64)                // zero dummy row NN (256 B)
            ((uint32*)&g1[(size_t)NN * N])[tid] = 0u;

        #pragma unroll
        for (int c = 0; c < 8; c++) {
            int idx = c * 1024 + tid * 4;
            int r = idx >> 7, col = idx & 127;
            int ra = row0 + r;
            float4 v = (ra < M) ? *(const float4*)&x[(size_t)ra * K + col]
                                : make_float4(0.f, 0.f, 0.f, 0.f);
            ushort4 bq;
            bq.x = f2bf(v.x); bq.y = f2bf(v.y); bq.z = f2bf(v.z); bq.w = f2bf(v.w);
            *(ushort4*)&As[r * LDA + col] = bq;
        }
        #pragma unroll
        for (int c = 0; c < (K * N) / 1024; c++) {
            int idx = c * 1024 + tid * 4;
            int k = idx >> 7, n = idx & (N - 1);
            float4 v = *(const float4*)&W1[idx];
            Bt[(n + 0) * LDA + k] = f2bf(v.x);
            Bt[(n + 1) * LDA + k] = f2bf(v.y);
            Bt[(n + 2) * LDA + k] = f2bf(v.z);
            Bt[(n + 3) * LDA + k] = f2bf(v.w);
        }
        __syncthreads();

        int lane = tid & 63;
        int wv = tid >> 6;
        int m0 = wv * 16;
        int ml = lane & 15;
        int quad = lane >> 4;

        f32x4 acc[NT];
        #pragma unroll
        for (int i = 0; i < NT; i++) acc[i] = (f32x4){0.f, 0.f, 0.f, 0.f};

        #pragma unroll
        for (int ks = 0; ks < 4; ks++) {
            int kof = ks * 32 + quad * 8;
            bf16x8 a = ld_frag8(&As[(m0 + ml) * LDA + kof]);
            #pragma unroll
            for (int nt = 0; nt < NT; nt++) {
                bf16x8 bb = ld_frag8(&Bt[(nt * 16 + ml) * LDA + kof]);
                acc[nt] = __builtin_amdgcn_mfma_f32_16x16x32_bf16(a, bb, acc[nt], 0, 0, 0);
            }
        }

        #pragma unroll
        for (int r = 0; r < 4; r++) {
            int row = row0 + m0 + quad * 4 + r;
            if (row < M) {
                #pragma unroll
                for (int nt = 0; nt < NT; nt++)
                    g1[(size_t)row * N + nt * 16 + ml] = f2bf(acc[nt][r]);
            }
        }
    }
}

// ---------------------------------------------------------------------------
// bucket_finish: per bucket -- staged edges -> LDS (one read), LDS degree
// count, local scan, ONE global atomicAdd to allocate the bucket's compact
// ssrc region, fine scatter + pad fill. Also writes dis[NN] = 0 (dummy node).
// ---------------------------------------------------------------------------
__global__ __launch_bounds__(256) void bucket_finish_kernel(
        const uint32* __restrict__ staging, const int* __restrict__ gcursor,
        int* __restrict__ gedge, int* __restrict__ deg, float* __restrict__ dis,
        int* __restrict__ row_start, int* __restrict__ ssrc) {
    __shared__ uint32 pairs[CAP];        // 16 KB
    __shared__ int cnt[1 << BSH];
    __shared__ int sb[1 << BSH];
    __shared__ int cur[1 << BSH];
    __shared__ int pend[1 << BSH];
    __shared__ int bbase;
    int b = blockIdx.x;
    int node0 = b << BSH;
    int tid = threadIdx.x;
    int n_edges = gcursor[b];

    if (tid < (1 << BSH)) cnt[tid] = 0;
    __syncthreads();

    for (int i = tid; i < n_edges; i += 256) {
        uint32 p = staging[(size_t)b * CAP + i];
        pairs[i] = p;
        atomicAdd(&cnt[p & 127u], 1);
    }
    __syncthreads();

    int p = 0;
    if (tid < (1 << BSH)) {
        int node = node0 + tid;
        int c = cnt[tid];
        if (node < NN) {
            deg[node] = c;
            dis[node] = (c > 0) ? rsqrtf((float)c) : 0.0f;
            p = (c + 7) & ~7;
        } else if (node == NN) {
            dis[NN] = 0.0f;              // dummy node scale (finite, zero)
        }
        sb[tid] = p;
    }
    __syncthreads();
    #pragma unroll
    for (int off = 1; off < (1 << BSH); off <<= 1) {
        int t = (tid >= off && tid < (1 << BSH)) ? sb[tid - off] : 0;
        __syncthreads();
        if (tid < (1 << BSH)) sb[tid] += t;
        __syncthreads();
    }
    if (tid == (1 << BSH) - 1) bbase = atomicAdd(gedge, sb[tid]);
    __syncthreads();

    if (tid < (1 << BSH)) {
        int rs = bbase + sb[tid] - p;    // exclusive
        cur[tid] = rs;
        pend[tid] = rs + p;
        int node = node0 + tid;
        if (node < NN) row_start[node] = rs;
    }
    __syncthreads();

    for (int i = tid; i < n_edges; i += 256) {
        uint32 pr = pairs[i];
        int off = atomicAdd(&cur[pr & 127u], 1);
        ssrc[off] = (int)(pr >> 7);
    }
    __syncthreads();

    if (tid < (1 << BSH)) {
        int node = node0 + tid;
        if (node < NN) {
            for (int q = cur[tid]; q < pend[tid]; q++) ssrc[q] = NN;   // dummy -> zero row
        }
    }
}

// ---------------------------------------------------------------------------
// FUSED aggregation layer 1 + layer-2 GEMM:
// Block = 32 nodes (4 waves x 8 sequential nodes). Per node: one wave gathers
// dis[src]*g1[src] (predicated preload of <=64 edge indices + scales),
// reduces, applies bias+ReLU, stores bf16 h-row into LDS H[32][132].
// After one barrier: 32x128 @ 128x64 mini-GEMM (W2 staged as Bt in LDS,
// verified fragment layout, 8 MFMA/wave) -> g2 = bf16(dis[row] * (h @ W2)).
// Deletes the gemm64 dispatch and the 51.2 MB h round-trip.
// ---------------------------------------------------------------------------
__global__ __launch_bounds__(256) void agg128f_kernel(
        const ushort16* __restrict__ g1, const int* __restrict__ row_start,
        const int* __restrict__ deg, const int* __restrict__ ssrc,
        const float* __restrict__ dis, const float* __restrict__ b1,
        const float* __restrict__ W2, ushort16* __restrict__ g2) {
    constexpr int LDA = 132;
    __shared__ ushort16 Bt[64 * LDA];     // W2^T bf16: Bt[n][k], 16.9 KB
    __shared__ ushort16 H[32 * LDA];      // 32 h rows bf16, 8.4 KB
    __shared__ float sdis[32];

    int tid = threadIdx.x;
    int lane = tid & 63, wv = tid >> 6;
    int node0 = blockIdx.x * 32;

    // stage Bt[n][k] = bf16(W2[k][n])   (W2 is f32 [128][64])
    #pragma unroll
    for (int c = 0; c < 8; c++) {            // (128*64)/1024
        int idx = c * 1024 + tid * 4;
        int k = idx >> 6, n = idx & 63;
        float4 v = *(const float4*)&W2[idx];
        Bt[(n + 0) * LDA + k] = f2bf(v.x);
        Bt[(n + 1) * LDA + k] = f2bf(v.y);
        Bt[(n + 2) * LDA + k] = f2bf(v.z);
        Bt[(n + 3) * LDA + k] = f2bf(v.w);
    }
    // zero g2 dummy row NN (128 B) -- staging (same region) is dead by now
    if (blockIdx.x == 0 && tid < 32)
        ((uint32*)&g2[(size_t)NN * 64])[tid] = 0u;

    int fl = lane & 15;            // feature octet
    int q  = lane >> 4;            // edge sub-slot 0..3
    int laneoff = fl * 16;
    const char* gb = (const char*)g1;

    for (int it = 0; it < 8; it++) {
        int node = node0 + it * 4 + wv;
        int beg = row_start[node];
        int ecount = (deg[node] + 7) & ~7;   // padded degree
        float sc = dis[node];

        // predicated preload: only active lanes touch ssrc/dis
        int ecl = (ecount < 64) ? ecount : 64;
        bool act = lane < ecl;
        int idx = act ? ssrc[beg + lane] : (int)NN;
        float dsv = act ? dis[idx] : 0.f;

        float a0 = 0.f, a1 = 0.f, a2 = 0.f, a3 = 0.f;
        float a4 = 0.f, a5 = 0.f, a6 = 0.f, a7 = 0.f;

        int nb = ecl >> 3;
        int b = 0;
        for (; b + 2 <= nb; b += 2) {
            int s0a = __shfl(idx, b * 8 + q);
            int s1a = __shfl(idx, b * 8 + 4 + q);
            int s0b = __shfl(idx, b * 8 + 8 + q);
            int s1b = __shfl(idx, b * 8 + 12 + q);
            float d0a = __shfl(dsv, b * 8 + q);
            float d1a = __shfl(dsv, b * 8 + 4 + q);
            float d0b = __shfl(dsv, b * 8 + 8 + q);
            float d1b = __shfl(dsv, b * 8 + 12 + q);
            uint4 v0a = *(const uint4*)(gb + (((uint32)s0a << 8) + laneoff));
            uint4 v1a = *(const uint4*)(gb + (((uint32)s1a << 8) + laneoff));
            uint4 v0b = *(const uint4*)(gb + (((uint32)s0b << 8) + laneoff));
            uint4 v1b = *(const uint4*)(gb + (((uint32)s1b << 8) + laneoff));
            ACC8S(v0a, d0a); ACC8S(v1a, d1a); ACC8S(v0b, d0b); ACC8S(v1b, d1b);
        }
        if (b < nb) {
            int s0 = __shfl(idx, b * 8 + q);
            int s1 = __shfl(idx, b * 8 + 4 + q);
            float d0 = __shfl(dsv, b * 8 + q);
            float d1 = __shfl(dsv, b * 8 + 4 + q);
            uint4 v0 = *(const uint4*)(gb + (((uint32)s0 << 8) + laneoff));
            uint4 v1 = *(const uint4*)(gb + (((uint32)s1 << 8) + laneoff));
            ACC8S(v0, d0); ACC8S(v1, d1);
        }
        // Rare tail: rows with more than 64 edges (all entries valid <= NN)
        for (int e = beg + 64; e < beg + ecount; e += 8) {
            int idx2 = ssrc[e + (lane & 7)];
            float dsv2 = dis[idx2];
            int s0 = __shfl(idx2, q);
            int s1 = __shfl(idx2, 4 + q);
            float d0 = __shfl(dsv2, q);
            float d1 = __shfl(dsv2, 4 + q);
            uint4 v0 = *(const uint4*)(gb + (((uint32)s0 << 8) + laneoff));
            uint4 v1 = *(const uint4*)(gb + (((uint32)s1 << 8) + laneoff));
            ACC8S(v0, d0); ACC8S(v1, d1);
        }

        // tree-combine the 4 quad partial sums
        a0 += __shfl_xor(a0, 16); a1 += __shfl_xor(a1, 16);
        a2 += __shfl_xor(a2, 16); a3 += __shfl_xor(a3, 16);
        a4 += __shfl_xor(a4, 16); a5 += __shfl_xor(a5, 16);
        a6 += __shfl_xor(a6, 16); a7 += __shfl_xor(a7, 16);
        a0 += __shfl_xor(a0, 32); a1 += __shfl_xor(a1, 32);
        a2 += __shfl_xor(a2, 32); a3 += __shfl_xor(a3, 32);
        a4 += __shfl_xor(a4, 32); a5 += __shfl_xor(a5, 32);
        a6 += __shfl_xor(a6, 32); a7 += __shfl_xor(a7, 32);

        int hrow = it * 4 + wv;
        if (lane == 0) sdis[hrow] = sc;
        if (lane < 16) {
            float4 bA = *(const float4*)&b1[fl * 8];
            float4 bB = *(const float4*)&b1[fl * 8 + 4];
            float o0 = fmaxf(sc * a0 + bA.x, 0.f);
            float o1 = fmaxf(sc * a1 + bA.y, 0.f);
            float o2 = fmaxf(sc * a2 + bA.z, 0.f);
            float o3 = fmaxf(sc * a3 + bA.w, 0.f);
            float o4 = fmaxf(sc * a4 + bB.x, 0.f);
            float o5 = fmaxf(sc * a5 + bB.y, 0.f);
            float o6 = fmaxf(sc * a6 + bB.z, 0.f);
            float o7 = fmaxf(sc * a7 + bB.w, 0.f);
            uint32 p0 = ((uint32)f2bf(o1) << 16) | (uint32)f2bf(o0);
            uint32 p1 = ((uint32)f2bf(o3) << 16) | (uint32)f2bf(o2);
            uint32 p2 = ((uint32)f2bf(o5) << 16) | (uint32)f2bf(o4);
            uint32 p3 = ((uint32)f2bf(o7) << 16) | (uint32)f2bf(o6);
            *(uint2*)&H[hrow * LDA + fl * 8]     = make_uint2(p0, p1);
            *(uint2*)&H[hrow * LDA + fl * 8 + 4] = make_uint2(p2, p3);
        }
    }
    __syncthreads();

    // mini-GEMM: g2[32 x 64] = dis * (H[32 x 128] @ W2)
    // wave wv: M-tile (wv&1), N-tiles (wv>>1)*2 .. +1
    int m0 = (wv & 1) * 16;
    int nt0 = (wv >> 1) * 2;
    int ml = lane & 15;
    int quad = lane >> 4;

    f32x4 acc[2];
    acc[0] = (f32x4){0.f, 0.f, 0.f, 0.f};
    acc[1] = (f32x4){0.f, 0.f, 0.f, 0.f};

    #pragma unroll
    for (int ks = 0; ks < 4; ks++) {
        int kof = ks * 32 + quad * 8;
        bf16x8 a = ld_frag8(&H[(m0 + ml) * LDA + kof]);
        #pragma unroll
        for (int t = 0; t < 2; t++) {
            bf16x8 bb = ld_frag8(&Bt[((nt0 + t) * 16 + ml) * LDA + kof]);
            acc[t] = __builtin_amdgcn_mfma_f32_16x16x32_bf16(a, bb, acc[t], 0, 0, 0);
        }
    }

    #pragma unroll
    for (int r = 0; r < 4; r++) {
        int row = m0 + quad * 4 + r;
        float s = sdis[row];
        size_t gbase = (size_t)(node0 + row) * 64;
        #pragma unroll
        for (int t = 0; t < 2; t++)
            g2[gbase + (nt0 + t) * 16 + ml] = f2bf(acc[t][r] * s);
    }
}

// ---------------------------------------------------------------------------
// Aggregation layer 2: F=64, bf16 gather -> f32 out (no activation).
// Half-wave per node (unchanged R11 form; g2 carries dis[src]·(h@W2)).
// ---------------------------------------------------------------------------
__global__ __launch_bounds__(256) void agg64_kernel(
        const ushort16* __restrict__ g, const int* __restrict__ row_start,
        const int* __restrict__ deg, const int* __restrict__ ssrc,
        const float* __restrict__ dis, const float* __restrict__ bias,
        float* __restrict__ out) {
    int wave = (blockIdx.x * 256 + threadIdx.x) >> 6;
    int lane = threadIdx.x & 63;
    int half = lane >> 5;
    int l2 = lane & 31;
    int node = wave * 2 + half;          // NN even => both halves valid
    if (node >= NN) return;

    int beg = row_start[node];
    int ecount = (deg[node] + 7) & ~7;   // padded degree
    float sc = dis[node];

    int fl = l2 & 7;               // feature octet: feats fl*8..fl*8+7
    int q  = l2 >> 3;              // edge sub-slot 0..3
    int laneoff = fl * 16;         // byte offset within a 128B row

    int idx = ssrc[beg + l2];

    float a0 = 0.f, a1 = 0.f, a2 = 0.f, a3 = 0.f;
    float a4 = 0.f, a5 = 0.f, a6 = 0.f, a7 = 0.f;

    const char* gb = (const char*)g;
    int nb = ((ecount < 32) ? ecount : 32) >> 3;
    int b = 0;
    for (; b + 2 <= nb; b += 2) {
        int s0a = __shfl(idx, half * 32 + b * 8 + q);
        int s1a = __shfl(idx, half * 32 + b * 8 + 4 + q);
        int s0b = __shfl(idx, half * 32 + b * 8 + 8 + q);
        int s1b = __shfl(idx, half * 32 + b * 8 + 12 + q);
        uint4 v0a = *(const uint4*)(gb + (((uint32)s0a << 7) + laneoff));
        uint4 v1a = *(const uint4*)(gb + (((uint32)s1a << 7) + laneoff));
        uint4 v0b = *(const uint4*)(gb + (((uint32)s0b << 7) + laneoff));
        uint4 v1b = *(const uint4*)(gb + (((uint32)s1b << 7) + laneoff));
        ACC8(v0a); ACC8(v1a); ACC8(v0b); ACC8(v1b);
    }
    if (b < nb) {
        int s0 = __shfl(idx, half * 32 + b * 8 + q);
        int s1 = __shfl(idx, half * 32 + b * 8 + 4 + q);
        uint4 v0 = *(const uint4*)(gb + (((uint32)s0 << 7) + laneoff));
        uint4 v1 = *(const uint4*)(gb + (((uint32)s1 << 7) + laneoff));
        ACC8(v0); ACC8(v1);
    }
    for (int e = beg + 32; e < beg + ecount; e += 8) {
        int idx2 = ssrc[e + (l2 & 7)];
        int s0 = __shfl(idx2, half * 32 + q);
        int s1 = __shfl(idx2, half * 32 + 4 + q);
        uint4 v0 = *(const uint4*)(gb + (((uint32)s0 << 7) + laneoff));
        uint4 v1 = *(const uint4*)(gb + (((uint32)s1 << 7) + laneoff));
        ACC8(v0); ACC8(v1);
    }

    a0 += __shfl_xor(a0, 8);  a1 += __shfl_xor(a1, 8);
    a2 += __shfl_xor(a2, 8);  a3 += __shfl_xor(a3, 8);
    a4 += __shfl_xor(a4, 8);  a5 += __shfl_xor(a5, 8);
    a6 += __shfl_xor(a6, 8);  a7 += __shfl_xor(a7, 8);
    a0 += __shfl_xor(a0, 16); a1 += __shfl_xor(a1, 16);
    a2 += __shfl_xor(a2, 16); a3 += __shfl_xor(a3, 16);
    a4 += __shfl_xor(a4, 16); a5 += __shfl_xor(a5, 16);
    a6 += __shfl_xor(a6, 16); a7 += __shfl_xor(a7, 16);

    if (l2 < 8) {
        float4 bA = *(const float4*)&bias[fl * 8];
        float4 bB = *(const float4*)&bias[fl * 8 + 4];
        float4 oA = make_float4(sc * a0 + bA.x, sc * a1 + bA.y,
                                sc * a2 + bA.z, sc * a3 + bA.w);
        float4 oB = make_float4(sc * a4 + bB.x, sc * a5 + bB.y,
                                sc * a6 + bB.z, sc * a7 + bB.w);
        *(float4*)&out[(size_t)node * 64 + fl * 8]     = oA;
        *(float4*)&out[(size_t)node * 64 + fl * 8 + 4] = oB;
    }
}

// ---------------------------------------------------------------------------
// Launch. Workspace ~48.8 MB. staging (12.81 MB) and g2 (12.80 MB +128B)
// share one region: staging dead after bucket_finish; g2 written by agg128f.
// h buffer deleted entirely (layer-2 GEMM fused into agg128f).
// ---------------------------------------------------------------------------
extern "C" void kernel_launch(void* const* d_in, const int* in_sizes, int n_in,
                              void* d_out, int out_size, void* d_ws, size_t ws_size,
                              hipStream_t stream) {
    const float* x  = (const float*)d_in[0];
    const int*   ei = (const int*)d_in[1];
    const float* W1 = (const float*)d_in[2];
    const float* b1 = (const float*)d_in[3];
    const float* W2 = (const float*)d_in[4];
    const float* b2 = (const float*)d_in[5];
    float* out = (float*)d_out;

    char* ws = (char*)d_ws;
    size_t off = 0;
    auto alloc = [&](size_t bytes) {
        void* p = ws + off;
        off = (off + bytes + 255) & ~(size_t)255;
        return p;
    };

    int*      deg_i      = (int*)alloc(NN * 4);
    float*    dis        = (float*)alloc((NN + 1) * 4);   // +1: dis[NN] = 0
    int*      row_start  = (int*)alloc(NN * 4);
    int*      gcursor    = (int*)alloc((NBKT + 1) * 4);   // +1: gedge cursor
    int*      ssrc       = (int*)alloc((size_t)PADE * 4); // 9.2 MB
    ushort16* g1         = (ushort16*)alloc((size_t)(NN + 1) * 128 * 2);  // 25.6 MB
    // staging (12.81 MB) / g2 ((NN+1)*64*2 = 12.80 MB) share one region
    char*     big        = (char*)alloc((size_t)NBKT * CAP * 4);
    uint32*   staging    = (uint32*)big;
    ushort16* g2         = (ushort16*)big;
    int*      gedge      = gcursor + NBKT;

    hipMemsetAsync(gcursor, 0, (NBKT + 1) * 4, stream);

    // [CSR binning  ||  layer-1 GEMM] in one launch (independent inputs)
    binxgemm_kernel<<<BIN_BLOCKS + (NN + 63) / 64, 256, 0, stream>>>(
        ei, gcursor, staging, x, W1, g1, NN);

    bucket_finish_kernel<<<NBKT, 256, 0, stream>>>(
        staging, gcursor, gedge, deg_i, dis, row_start, ssrc);

    // fused agg1 + layer-2 GEMM: 3125 blocks x 32 nodes
    agg128f_kernel<<<NN / 32, 256, 0, stream>>>(
        g1, row_start, deg_i, ssrc, dis, b1, W2, g2);

    const int AGG2_BLOCKS = (NN / 2 + 3) / 4; // 12500 (half-wave per node)
    agg64_kernel<<<AGG2_BLOCKS, 256, 0, stream>>>(g2, row_start, deg_i, ssrc, dis, b2, out);
}